// Round 8
// baseline (1067.620 us; speedup 1.0000x reference)
//
#include <hip/hip_runtime.h>
#include <hip/hip_bf16.h>

typedef __bf16 bf16x8 __attribute__((ext_vector_type(8)));
typedef float f32x4 __attribute__((ext_vector_type(4)));
typedef float f32x16 __attribute__((ext_vector_type(16)));
typedef int int4v __attribute__((ext_vector_type(4)));
typedef unsigned int uint4v __attribute__((ext_vector_type(4)));
typedef unsigned short u16x8 __attribute__((ext_vector_type(8)));

#define N_NODES 8192
#define D_FEAT 128

// DIAGNOSTIC ROUND. Real path = round-6 best (157.6us), unchanged. Two
// probe dispatches (>380us each) are launched first so they land in the
// rocprof top-5 and expose real counters:
//   probe_read: fused kernel's A-access pattern, loads only, x10 reps.
//   probe_fused: round-6 fused body x6 reps (alternating layers, scratch).

// ---------------------------------------------------------------------------
__device__ __forceinline__ bf16x8 unpack_byte(unsigned dword, int sh) {
  unsigned P = ((dword >> sh) & 0xFFu) * 0x8001u;
  uint4v c;
  c[0] = (P & 0x10001u) * 0x3F80u;
  c[1] = ((P >> 2) & 0x10001u) * 0x3F80u;
  c[2] = ((P >> 4) & 0x10001u) * 0x3F80u;
  c[3] = ((P >> 6) & 0x10001u) * 0x3F80u;
  return __builtin_bit_cast(bf16x8, c);
}

// ---------------------------------------------------------------------------
// Bpk fragment build (verified rounds 2-6). Fragment f = kk*256 + ng*64 + l
// holds, at element e: F[sigma(kk*16 + (l>>5)*8 + e)][ng*32 + (l&31)],
// sigma(p) = 256*(p>>8) + 32*((p>>3)&7) + 4*(p&7) + ((p>>6)&3)
__device__ __forceinline__ void bpk32_store(const float* __restrict__ src,
                                            unsigned short* __restrict__ Bpk,
                                            int W) {
  const int kk = W >> 8;
  const int ng = (W >> 6) & 3;
  const int l = W & 63;
  const int d = ng * 32 + (l & 31);
  const int p0 = kk * 16 + (l >> 5) * 8;
  const int n0 = (p0 >> 8) * 256 + ((p0 >> 3) & 7) * 32 + ((p0 >> 6) & 3);
  u16x8 pk;
#pragma unroll
  for (int e = 0; e < 8; ++e) {
    __bf16 v = (__bf16)src[(long)(n0 + 4 * e) * D_FEAT + d];
    pk[e] = __builtin_bit_cast(unsigned short, v);
  }
  *(u16x8*)(Bpk + (long)W * 8) = pk;
}

__global__ __launch_bounds__(256) void bpk_build32_kernel(
    const float* __restrict__ src, unsigned short* __restrict__ Bpk) {
  bpk32_store(src, Bpk, blockIdx.x * 256 + threadIdx.x);
}

// ---------------------------------------------------------------------------
// Round-6 fused layer body (verified): block = 32 rows x 128 cols, 512 thr
// = 8 waves = 4 ng x 2 kh2; 32 chunks of 256 ints/row.
__device__ __forceinline__ void fused_layer_body(
    const int* __restrict__ adj, const unsigned short* __restrict__ Bpk,
    const float* __restrict__ fin, float* __restrict__ fout,
    unsigned (*bitsL)[320], int* degL, f32x4 (*red)[4][64]) {
  const int tid = threadIdx.x;
  const int lane = tid & 63;
  const int w = tid >> 6;       // 0..7
  const int ng = w & 3;         // 32-col group
  const int kh2 = w >> 2;       // K-half of each chunk
  const int l31 = lane & 31;
  const int lh = lane >> 5;
  const int lh8 = lh * 8;
  const int m0 = blockIdx.x * 32;

  const int4v* aB0 = (const int4v*)(adj + ((long)(m0 + w) << 13)) + lane;
  const int4v* aB1 = (const int4v*)(adj + ((long)(m0 + 8 + w) << 13)) + lane;
  const int4v* aB2 = (const int4v*)(adj + ((long)(m0 + 16 + w) << 13)) + lane;
  const int4v* aB3 = (const int4v*)(adj + ((long)(m0 + 24 + w) << 13)) + lane;

  int cnt0 = 0, cnt1 = 0, cnt2 = 0, cnt3 = 0;

#define DO_BALLOT(R0, R1, R2, R3, BUF)                                       \
  {                                                                          \
    const int e_ = lane >> 1;                                                \
    _Pragma("unroll") for (int i = 0; i < 4; ++i) {                          \
      int4v vv = (i == 0) ? (R0) : (i == 1) ? (R1) : (i == 2) ? (R2) : (R3); \
      unsigned long long b0 = __ballot(vv[0] != 0);                          \
      unsigned long long b1 = __ballot(vv[1] != 0);                          \
      unsigned long long b2 = __ballot(vv[2] != 0);                          \
      unsigned long long b3 = __ballot(vv[3] != 0);                          \
      int pc = __popcll(b0) + __popcll(b1) + __popcll(b2) + __popcll(b3);    \
      if (i == 0) cnt0 += pc;                                                \
      if (i == 1) cnt1 += pc;                                                \
      if (i == 2) cnt2 += pc;                                                \
      if (i == 3) cnt3 += pc;                                                \
      unsigned long long bsel = b0;                                          \
      if (e_ == 1) bsel = b1;                                                \
      if (e_ == 2) bsel = b2;                                                \
      if (e_ == 3) bsel = b3;                                                \
      unsigned dv = (lane & 1) ? (unsigned)(bsel >> 32) : (unsigned)bsel;    \
      if (lane < 8) bitsL[BUF][(i * 8 + w) * 10 + lane] = dv;                \
    }                                                                        \
  }

  f32x16 acc = {0.f, 0.f, 0.f, 0.f, 0.f, 0.f, 0.f, 0.f,
                0.f, 0.f, 0.f, 0.f, 0.f, 0.f, 0.f, 0.f};

#define DO_GEMM(C, BUF)                                                      \
  {                                                                          \
    const bf16x8* bp = (const bf16x8*)Bpk +                                  \
                       (((long)((C)*16 + kh2 * 8)) << 8) + ng * 64 + lane;   \
    bf16x8 bv0 = bp[0], bv1 = bp[256], bv2 = bp[512], bv3 = bp[768];         \
    bf16x8 bv4 = bp[1024], bv5 = bp[1280], bv6 = bp[1536], bv7 = bp[1792];   \
    const unsigned* bl = &bitsL[BUF][l31 * 10 + kh2 * 4];                    \
    unsigned q0 = bl[0], q1 = bl[1], q2 = bl[2], q3 = bl[3];                 \
    acc = __builtin_amdgcn_mfma_f32_32x32x16_bf16(unpack_byte(q0, lh8),      \
                                                  bv0, acc, 0, 0, 0);        \
    acc = __builtin_amdgcn_mfma_f32_32x32x16_bf16(unpack_byte(q0, lh8 + 16), \
                                                  bv1, acc, 0, 0, 0);        \
    acc = __builtin_amdgcn_mfma_f32_32x32x16_bf16(unpack_byte(q1, lh8),      \
                                                  bv2, acc, 0, 0, 0);        \
    acc = __builtin_amdgcn_mfma_f32_32x32x16_bf16(unpack_byte(q1, lh8 + 16), \
                                                  bv3, acc, 0, 0, 0);        \
    acc = __builtin_amdgcn_mfma_f32_32x32x16_bf16(unpack_byte(q2, lh8),      \
                                                  bv4, acc, 0, 0, 0);        \
    acc = __builtin_amdgcn_mfma_f32_32x32x16_bf16(unpack_byte(q2, lh8 + 16), \
                                                  bv5, acc, 0, 0, 0);        \
    acc = __builtin_amdgcn_mfma_f32_32x32x16_bf16(unpack_byte(q3, lh8),      \
                                                  bv6, acc, 0, 0, 0);        \
    acc = __builtin_amdgcn_mfma_f32_32x32x16_bf16(unpack_byte(q3, lh8 + 16), \
                                                  bv7, acc, 0, 0, 0);        \
  }

  int4v avA0 = aB0[0], avA1 = aB1[0], avA2 = aB2[0], avA3 = aB3[0];
  int4v avB0 = aB0[64], avB1 = aB1[64], avB2 = aB2[64], avB3 = aB3[64];
  DO_BALLOT(avA0, avA1, avA2, avA3, 0)
  __syncthreads();

#define BODY(C, CUR0, CUR1, CUR2, CUR3, OTH0, OTH1, OTH2, OTH3)              \
  {                                                                          \
    if ((C) + 2 < 32) {                                                      \
      CUR0 = aB0[((C) + 2) * 64];                                            \
      CUR1 = aB1[((C) + 2) * 64];                                            \
      CUR2 = aB2[((C) + 2) * 64];                                            \
      CUR3 = aB3[((C) + 2) * 64];                                            \
    }                                                                        \
    if ((C) + 1 < 32) DO_BALLOT(OTH0, OTH1, OTH2, OTH3, ((C) + 1) & 1)       \
    DO_GEMM((C), (C)&1)                                                      \
    __syncthreads();                                                         \
  }

  for (int c = 0; c < 32; c += 2) {
    BODY(c, avA0, avA1, avA2, avA3, avB0, avB1, avB2, avB3)
    BODY(c + 1, avB0, avB1, avB2, avB3, avA0, avA1, avA2, avA3)
  }
#undef BODY
#undef DO_GEMM
#undef DO_BALLOT

  if (lane == 0) {
    degL[w] = cnt0;
    degL[8 + w] = cnt1;
    degL[16 + w] = cnt2;
    degL[24 + w] = cnt3;
  }

  if (kh2) {
#define ST4(c)                                                               \
  red[ng][c][lane] = __builtin_shufflevector(acc, acc, 4 * (c), 4 * (c) + 1, \
                                             4 * (c) + 2, 4 * (c) + 3);
    ST4(0) ST4(1) ST4(2) ST4(3)
#undef ST4
  }
  __syncthreads();
  if (!kh2) {
#pragma unroll
    for (int c = 0; c < 4; ++c) {
      f32x4 r = red[ng][c][lane];
#pragma unroll
      for (int k = 0; k < 4; ++k) acc[4 * c + k] += r[k];
    }
#pragma unroll
    for (int r = 0; r < 16; ++r) {
      const int row32 = (r & 3) + 8 * (r >> 2) + 4 * lh;
      const int row = m0 + row32;
      const int dg = degL[row32];
      const long off = (long)row * D_FEAT + ng * 32 + l31;
      fout[off] = dg > 0 ? acc[r] * (1.0f / (float)dg) : fin[off];
    }
  }
}

// ---------------------------------------------------------------------------
__global__ __launch_bounds__(512, 2) void fused_layer_kernel(
    const int* __restrict__ adj, const unsigned short* __restrict__ Bpk,
    const float* __restrict__ fin, float* __restrict__ fout) {
  __shared__ unsigned bitsL[2][320];
  __shared__ int degL[32];
  __shared__ __align__(16) f32x4 red[4][4][64];
  fused_layer_body(adj, Bpk, fin, fout, bitsL, degL, red);
}

// ---------------------------------------------------------------------------
// PROBE 1: round-6 fused body x6 reps, alternating layers (defeats L3),
// writing scratch. One dispatch ~450us -> lands in rocprof top-5.
__global__ __launch_bounds__(512, 2) void probe_fused_kernel(
    const int* __restrict__ adj, const unsigned short* __restrict__ Bpk,
    const float* __restrict__ fin, float* __restrict__ scratch) {
  __shared__ unsigned bitsL[2][320];
  __shared__ int degL[32];
  __shared__ __align__(16) f32x4 red[4][4][64];
  for (int r = 0; r < 6; ++r) {
    const int* a = adj + (long)(r & 1) * N_NODES * N_NODES;
    fused_layer_body(a, Bpk, fin, scratch, bitsL, degL, red);
    __syncthreads();
  }
}

// ---------------------------------------------------------------------------
// PROBE 2: pure streaming read, EXACT fused-kernel A-access pattern
// (block=32 rows, wave w rows {w,8+w,16+w,24+w}, 1 int4/lane/chunk),
// x10 reps alternating layers. ~2.5 GiB -> ~390-550us dispatch.
__global__ __launch_bounds__(512) void probe_read_kernel(
    const int* __restrict__ adj, int* __restrict__ sink) {
  const int tid = threadIdx.x;
  const int lane = tid & 63;
  const int w = tid >> 6;
  const int m0 = blockIdx.x * 32;
  int4v s = {0, 0, 0, 0};
  for (int r = 0; r < 10; ++r) {
    const int* a = adj + (long)(r & 1) * N_NODES * N_NODES;
    const int4v* p0 = (const int4v*)(a + ((long)(m0 + w) << 13)) + lane;
    const int4v* p1 = (const int4v*)(a + ((long)(m0 + 8 + w) << 13)) + lane;
    const int4v* p2 = (const int4v*)(a + ((long)(m0 + 16 + w) << 13)) + lane;
    const int4v* p3 = (const int4v*)(a + ((long)(m0 + 24 + w) << 13)) + lane;
#pragma unroll 4
    for (int c = 0; c < 32; ++c) {
      s += p0[c * 64];
      s += p1[c * 64];
      s += p2[c * 64];
      s += p3[c * 64];
    }
  }
  sink[blockIdx.x * 512 + tid] = s[0] + s[1] + s[2] + s[3];
}

// ---------------------------------------------------------------------------
// Fallback path (round-1 verified), used only if ws too small.
__global__ __launch_bounds__(256) void transpose_cast_kernel(
    const float* __restrict__ src, unsigned short* __restrict__ dst) {
  __shared__ float tile[64][129];
  const int t = threadIdx.x;
  const int nbase = blockIdx.x * 64;
#pragma unroll
  for (int i = 0; i < 32; ++i) {
    int idx = t + i * 256;
    int nl = idx >> 7;
    int d = idx & 127;
    tile[nl][d] = src[(long)(nbase + nl) * D_FEAT + d];
  }
  __syncthreads();
#pragma unroll
  for (int i = 0; i < 32; ++i) {
    int idx = t + i * 256;
    int d = idx >> 6;
    int nl = idx & 63;
    __bf16 b = (__bf16)tile[nl][d];
    dst[(long)d * N_NODES + nbase + nl] = __builtin_bit_cast(unsigned short, b);
  }
}

__global__ __launch_bounds__(512) void layer_kernel_direct(
    const int* __restrict__ adj, const unsigned short* __restrict__ BT,
    const float* __restrict__ fin, float* __restrict__ fout) {
  const int tid = threadIdx.x;
  const int lane = tid & 63;
  const int w = tid >> 6;
  const int m0 = blockIdx.x * 32 + (w >> 2) * 16;
  const int n0 = (w & 3) * 32;
  const int lr = lane & 15;
  const int kc = lane >> 4;

  const int4v* ap = (const int4v*)(adj + (long)(m0 + lr) * N_NODES + kc * 8);
  const bf16x8* bp0 = (const bf16x8*)(BT + (long)(n0 + lr) * N_NODES + kc * 8);
  const bf16x8* bp1 =
      (const bf16x8*)(BT + (long)(n0 + 16 + lr) * N_NODES + kc * 8);

  f32x4 acc0 = {0.f, 0.f, 0.f, 0.f};
  f32x4 acc1 = {0.f, 0.f, 0.f, 0.f};
  int degv = 0;

#pragma unroll 4
  for (int k = 0; k < N_NODES; k += 32) {
    int4v alo = ap[0];
    int4v ahi = ap[1];
    bf16x8 b0 = bp0[0];
    bf16x8 b1 = bp1[0];
    ap += 8;
    bp0 += 4;
    bp1 += 4;
    unsigned short u[8];
    u[0] = alo[0] ? 0x3F80 : 0;
    u[1] = alo[1] ? 0x3F80 : 0;
    u[2] = alo[2] ? 0x3F80 : 0;
    u[3] = alo[3] ? 0x3F80 : 0;
    u[4] = ahi[0] ? 0x3F80 : 0;
    u[5] = ahi[1] ? 0x3F80 : 0;
    u[6] = ahi[2] ? 0x3F80 : 0;
    u[7] = ahi[3] ? 0x3F80 : 0;
    degv += alo[0] + alo[1] + alo[2] + alo[3] + ahi[0] + ahi[1] + ahi[2] +
            ahi[3];
    bf16x8 a;
    memcpy(&a, u, 16);
    acc0 = __builtin_amdgcn_mfma_f32_16x16x32_bf16(a, b0, acc0, 0, 0, 0);
    acc1 = __builtin_amdgcn_mfma_f32_16x16x32_bf16(a, b1, acc1, 0, 0, 0);
  }

  degv += __shfl_xor(degv, 16);
  degv += __shfl_xor(degv, 32);
  int dgv[4];
#pragma unroll
  for (int j = 0; j < 4; ++j) dgv[j] = __shfl(degv, kc * 4 + j);

#pragma unroll
  for (int t = 0; t < 2; ++t) {
    const f32x4 acc = t ? acc1 : acc0;
    const int col = n0 + t * 16 + lr;
#pragma unroll
    for (int j = 0; j < 4; ++j) {
      const long off = (long)(m0 + kc * 4 + j) * D_FEAT + col;
      fout[off] = dgv[j] > 0 ? acc[j] * (1.0f / (float)dgv[j]) : fin[off];
    }
  }
}

// ---------------------------------------------------------------------------
extern "C" void kernel_launch(void* const* d_in, const int* in_sizes, int n_in,
                              void* d_out, int out_size, void* d_ws,
                              size_t ws_size, hipStream_t stream) {
  const float* features = (const float*)d_in[0];
  const int* adj = (const int*)d_in[1];
  float* out = (float*)d_out;
  const long NN = (long)N_NODES * N_NODES;

  const size_t BPK_BYTES = (size_t)D_FEAT * N_NODES * 2;      // 2 MiB
  const size_t SCR_BYTES = (size_t)N_NODES * D_FEAT * 4;      // 4 MiB
  const size_t SINK_BYTES = 256ul * 512 * 4;                  // 512 KiB
  const size_t NEED = BPK_BYTES + SCR_BYTES + SINK_BYTES;

  if (ws_size >= NEED) {
    unsigned short* Bpk = (unsigned short*)d_ws;
    float* scratch = (float*)((char*)d_ws + BPK_BYTES);
    int* sink = (int*)((char*)d_ws + BPK_BYTES + SCR_BYTES);

    // --- probes (counters land in rocprof top-5; writes only to ws) ---
    probe_read_kernel<<<256, 512, 0, stream>>>(adj, sink);
    bpk_build32_kernel<<<512, 256, 0, stream>>>(features, Bpk);
    probe_fused_kernel<<<256, 512, 0, stream>>>(adj, Bpk, features, scratch);

    // --- real path: round-6 best (157.6us) ---
    fused_layer_kernel<<<256, 512, 0, stream>>>(adj, Bpk, features, out);
    bpk_build32_kernel<<<512, 256, 0, stream>>>(out, Bpk);
    fused_layer_kernel<<<256, 512, 0, stream>>>(adj + NN, Bpk, out, out);
  } else {
    // Fallback: round-1 verified path (needs only 2 MiB ws)
    unsigned short* BTw = (unsigned short*)d_ws;
    transpose_cast_kernel<<<N_NODES / 64, 256, 0, stream>>>(features, BTw);
    layer_kernel_direct<<<N_NODES / 32, 512, 0, stream>>>(adj, BTw, features,
                                                          out);
    transpose_cast_kernel<<<N_NODES / 64, 256, 0, stream>>>(out, BTw);
    layer_kernel_direct<<<N_NODES / 32, 512, 0, stream>>>(adj + NN, BTw, out,
                                                          out);
  }
}

// Round 9
// 164.862 us; speedup vs baseline: 6.4758x; 6.4758x over previous
//
#include <hip/hip_runtime.h>
#include <hip/hip_bf16.h>

typedef __bf16 bf16x8 __attribute__((ext_vector_type(8)));
typedef float f32x4 __attribute__((ext_vector_type(4)));
typedef float f32x16 __attribute__((ext_vector_type(16)));
typedef int int4v __attribute__((ext_vector_type(4)));
typedef unsigned int uint4v __attribute__((ext_vector_type(4)));
typedef unsigned short u16x8 __attribute__((ext_vector_type(8)));

#define N_NODES 8192
#define D_FEAT 128

// Round-8 counters: fused A-pattern loads-only = 5.3 TB/s consumption at
// 21.5% occupancy (8 waves/CU, grid 256) -> occupancy-starved MLP. This
// round: split each layer across grid 512 = 256 rowblk x 2 K-halves
// (2 blocks/CU, 16 waves/CU). Partial C + partial deg to ws; combine
// kernel sums halves + deg-divide + deg==0 passthrough. Ballot / sigma /
// Bpk / GEMM formulas byte-identical to verified round 6.

// ---------------------------------------------------------------------------
__device__ __forceinline__ bf16x8 unpack_byte(unsigned dword, int sh) {
  unsigned P = ((dword >> sh) & 0xFFu) * 0x8001u;
  uint4v c;
  c[0] = (P & 0x10001u) * 0x3F80u;
  c[1] = ((P >> 2) & 0x10001u) * 0x3F80u;
  c[2] = ((P >> 4) & 0x10001u) * 0x3F80u;
  c[3] = ((P >> 6) & 0x10001u) * 0x3F80u;
  return __builtin_bit_cast(bf16x8, c);
}

// ---------------------------------------------------------------------------
// Bpk fragment build (verified rounds 2-6). Fragment f = kk*256 + ng*64 + l
// holds, at element e: F[sigma(kk*16 + (l>>5)*8 + e)][ng*32 + (l&31)],
// sigma(p) = 256*(p>>8) + 32*((p>>3)&7) + 4*(p&7) + ((p>>6)&3)
__device__ __forceinline__ void bpk32_store(const float* __restrict__ src,
                                            unsigned short* __restrict__ Bpk,
                                            int W) {
  const int kk = W >> 8;
  const int ng = (W >> 6) & 3;
  const int l = W & 63;
  const int d = ng * 32 + (l & 31);
  const int p0 = kk * 16 + (l >> 5) * 8;
  const int n0 = (p0 >> 8) * 256 + ((p0 >> 3) & 7) * 32 + ((p0 >> 6) & 3);
  u16x8 pk;
#pragma unroll
  for (int e = 0; e < 8; ++e) {
    __bf16 v = (__bf16)src[(long)(n0 + 4 * e) * D_FEAT + d];
    pk[e] = __builtin_bit_cast(unsigned short, v);
  }
  *(u16x8*)(Bpk + (long)W * 8) = pk;
}

__global__ __launch_bounds__(256) void bpk_build32_kernel(
    const float* __restrict__ src, unsigned short* __restrict__ Bpk) {
  bpk32_store(src, Bpk, blockIdx.x * 256 + threadIdx.x);
}

// ---------------------------------------------------------------------------
// Fused pack+GEMM, split-K2 across blocks. Grid 512 = 256 rowblk x 2 kh.
// Block: rows [32*rowblk, +32), all 128 cols, K-ints [kh*4096, +4096) in 16
// chunks of 256. 8 waves = 4 ng x 2 kh2 (intra-chunk K-half). Writes raw
// partial C (f32) and partial deg (u16); no divide here.
__global__ __launch_bounds__(512, 2) void fused_split2_kernel(
    const int* __restrict__ adj, const unsigned short* __restrict__ Bpk,
    float* __restrict__ pC, unsigned short* __restrict__ degP) {
  __shared__ unsigned bitsL[2][320];            // [buf][row*10 + slot]
  __shared__ __align__(16) f32x4 red[4][4][64]; // 16 KiB intra-block combine

  const int tid = threadIdx.x;
  const int lane = tid & 63;
  const int w = tid >> 6;       // 0..7
  const int ng = w & 3;
  const int kh2 = w >> 2;
  const int l31 = lane & 31;
  const int lh = lane >> 5;
  const int lh8 = lh * 8;

  const int bx = blockIdx.x;
  const int rowblk = bx >> 1;
  const int kh = bx & 1;        // K-half of the layer
  const int m0 = rowblk * 32;

  // A streams: wave w -> rows {w, 8+w, 16+w, 24+w}, cols [kh*4096, +4096).
  const int4v* aB0 =
      (const int4v*)(adj + ((long)(m0 + w) << 13) + kh * 4096) + lane;
  const int4v* aB1 =
      (const int4v*)(adj + ((long)(m0 + 8 + w) << 13) + kh * 4096) + lane;
  const int4v* aB2 =
      (const int4v*)(adj + ((long)(m0 + 16 + w) << 13) + kh * 4096) + lane;
  const int4v* aB3 =
      (const int4v*)(adj + ((long)(m0 + 24 + w) << 13) + kh * 4096) + lane;

  int cnt0 = 0, cnt1 = 0, cnt2 = 0, cnt3 = 0;

#define DO_BALLOT(R0, R1, R2, R3, BUF)                                       \
  {                                                                          \
    const int e_ = lane >> 1;                                                \
    _Pragma("unroll") for (int i = 0; i < 4; ++i) {                          \
      int4v vv = (i == 0) ? (R0) : (i == 1) ? (R1) : (i == 2) ? (R2) : (R3); \
      unsigned long long b0 = __ballot(vv[0] != 0);                          \
      unsigned long long b1 = __ballot(vv[1] != 0);                          \
      unsigned long long b2 = __ballot(vv[2] != 0);                          \
      unsigned long long b3 = __ballot(vv[3] != 0);                          \
      int pc = __popcll(b0) + __popcll(b1) + __popcll(b2) + __popcll(b3);    \
      if (i == 0) cnt0 += pc;                                                \
      if (i == 1) cnt1 += pc;                                                \
      if (i == 2) cnt2 += pc;                                                \
      if (i == 3) cnt3 += pc;                                                \
      unsigned long long bsel = b0;                                          \
      if (e_ == 1) bsel = b1;                                                \
      if (e_ == 2) bsel = b2;                                                \
      if (e_ == 3) bsel = b3;                                                \
      unsigned dv = (lane & 1) ? (unsigned)(bsel >> 32) : (unsigned)bsel;    \
      if (lane < 8) bitsL[BUF][(i * 8 + w) * 10 + lane] = dv;                \
    }                                                                        \
  }

  f32x16 acc = {0.f, 0.f, 0.f, 0.f, 0.f, 0.f, 0.f, 0.f,
                0.f, 0.f, 0.f, 0.f, 0.f, 0.f, 0.f, 0.f};

  // kk_global = kh*256 + C*16 + kh2*8 + kkl; consumption map verified r6.
#define DO_GEMM(C, BUF)                                                      \
  {                                                                          \
    const bf16x8* bp =                                                       \
        (const bf16x8*)Bpk +                                                 \
        (((long)(kh * 256 + (C)*16 + kh2 * 8)) << 8) + ng * 64 + lane;       \
    bf16x8 bv0 = bp[0], bv1 = bp[256], bv2 = bp[512], bv3 = bp[768];         \
    bf16x8 bv4 = bp[1024], bv5 = bp[1280], bv6 = bp[1536], bv7 = bp[1792];   \
    const unsigned* bl = &bitsL[BUF][l31 * 10 + kh2 * 4];                    \
    unsigned q0 = bl[0], q1 = bl[1], q2 = bl[2], q3 = bl[3];                 \
    acc = __builtin_amdgcn_mfma_f32_32x32x16_bf16(unpack_byte(q0, lh8),      \
                                                  bv0, acc, 0, 0, 0);        \
    acc = __builtin_amdgcn_mfma_f32_32x32x16_bf16(unpack_byte(q0, lh8 + 16), \
                                                  bv1, acc, 0, 0, 0);        \
    acc = __builtin_amdgcn_mfma_f32_32x32x16_bf16(unpack_byte(q1, lh8),      \
                                                  bv2, acc, 0, 0, 0);        \
    acc = __builtin_amdgcn_mfma_f32_32x32x16_bf16(unpack_byte(q1, lh8 + 16), \
                                                  bv3, acc, 0, 0, 0);        \
    acc = __builtin_amdgcn_mfma_f32_32x32x16_bf16(unpack_byte(q2, lh8),      \
                                                  bv4, acc, 0, 0, 0);        \
    acc = __builtin_amdgcn_mfma_f32_32x32x16_bf16(unpack_byte(q2, lh8 + 16), \
                                                  bv5, acc, 0, 0, 0);        \
    acc = __builtin_amdgcn_mfma_f32_32x32x16_bf16(unpack_byte(q3, lh8),      \
                                                  bv6, acc, 0, 0, 0);        \
    acc = __builtin_amdgcn_mfma_f32_32x32x16_bf16(unpack_byte(q3, lh8 + 16), \
                                                  bv7, acc, 0, 0, 0);        \
  }

  int4v avA0 = aB0[0], avA1 = aB1[0], avA2 = aB2[0], avA3 = aB3[0];
  int4v avB0 = aB0[64], avB1 = aB1[64], avB2 = aB2[64], avB3 = aB3[64];
  DO_BALLOT(avA0, avA1, avA2, avA3, 0)
  __syncthreads();

#define BODY(C, CUR0, CUR1, CUR2, CUR3, OTH0, OTH1, OTH2, OTH3)              \
  {                                                                          \
    if ((C) + 2 < 16) {                                                      \
      CUR0 = aB0[((C) + 2) * 64];                                            \
      CUR1 = aB1[((C) + 2) * 64];                                            \
      CUR2 = aB2[((C) + 2) * 64];                                            \
      CUR3 = aB3[((C) + 2) * 64];                                            \
    }                                                                        \
    if ((C) + 1 < 16) DO_BALLOT(OTH0, OTH1, OTH2, OTH3, ((C) + 1) & 1)       \
    DO_GEMM((C), (C)&1)                                                      \
    __syncthreads();                                                         \
  }

  for (int c = 0; c < 16; c += 2) {
    BODY(c, avA0, avA1, avA2, avA3, avB0, avB1, avB2, avB3)
    BODY(c + 1, avB0, avB1, avB2, avB3, avA0, avA1, avA2, avA3)
  }
#undef BODY
#undef DO_GEMM
#undef DO_BALLOT

  // Partial degrees for this K-half.
  if (lane == 0) {
    unsigned short* dp = degP + kh * N_NODES + m0;
    dp[w] = (unsigned short)cnt0;
    dp[8 + w] = (unsigned short)cnt1;
    dp[16 + w] = (unsigned short)cnt2;
    dp[24 + w] = (unsigned short)cnt3;
  }

  // Intra-block kh2 combine.
  if (kh2) {
#define ST4(c)                                                               \
  red[ng][c][lane] = __builtin_shufflevector(acc, acc, 4 * (c), 4 * (c) + 1, \
                                             4 * (c) + 2, 4 * (c) + 3);
    ST4(0) ST4(1) ST4(2) ST4(3)
#undef ST4
  }
  __syncthreads();
  if (kh2) return;
#pragma unroll
  for (int c = 0; c < 4; ++c) {
    f32x4 r = red[ng][c][lane];
#pragma unroll
    for (int k = 0; k < 4; ++k) acc[4 * c + k] += r[k];
  }

  // Raw partial C. C/D layout (m101): col = ng*32+l31,
  // row = m0 + (r&3) + 8*(r>>2) + 4*lh.
  float* base = pC + (long)kh * N_NODES * D_FEAT;
#pragma unroll
  for (int r = 0; r < 16; ++r) {
    const int row32 = (r & 3) + 8 * (r >> 2) + 4 * lh;
    base[(long)(m0 + row32) * D_FEAT + ng * 32 + l31] = acc[r];
  }
}

// ---------------------------------------------------------------------------
// Combine: out = deg>0 ? (pC0+pC1)/deg : fin.
__global__ __launch_bounds__(256) void combine2_kernel(
    const float* __restrict__ pC, const unsigned short* __restrict__ degP,
    const float* __restrict__ fin, float* __restrict__ fout) {
  const int g = blockIdx.x * 256 + threadIdx.x;  // f32x4 units, 0..262143
  const int row = g >> 5;
  const f32x4* P = (const f32x4*)pC;
  f32x4 s = P[g] + P[262144 + g];
  const int dg = (int)degP[row] + (int)degP[N_NODES + row];
  f32x4 o;
  if (dg > 0) {
    o = s * (1.0f / (float)dg);
  } else {
    o = ((const f32x4*)fin)[g];
  }
  ((f32x4*)fout)[g] = o;
}

// ---------------------------------------------------------------------------
// Fallback path (round-1 verified), used only if ws too small.
__global__ __launch_bounds__(256) void transpose_cast_kernel(
    const float* __restrict__ src, unsigned short* __restrict__ dst) {
  __shared__ float tile[64][129];
  const int t = threadIdx.x;
  const int nbase = blockIdx.x * 64;
#pragma unroll
  for (int i = 0; i < 32; ++i) {
    int idx = t + i * 256;
    int nl = idx >> 7;
    int d = idx & 127;
    tile[nl][d] = src[(long)(nbase + nl) * D_FEAT + d];
  }
  __syncthreads();
#pragma unroll
  for (int i = 0; i < 32; ++i) {
    int idx = t + i * 256;
    int d = idx >> 6;
    int nl = idx & 63;
    __bf16 b = (__bf16)tile[nl][d];
    dst[(long)d * N_NODES + nbase + nl] = __builtin_bit_cast(unsigned short, b);
  }
}

__global__ __launch_bounds__(512) void layer_kernel_direct(
    const int* __restrict__ adj, const unsigned short* __restrict__ BT,
    const float* __restrict__ fin, float* __restrict__ fout) {
  const int tid = threadIdx.x;
  const int lane = tid & 63;
  const int w = tid >> 6;
  const int m0 = blockIdx.x * 32 + (w >> 2) * 16;
  const int n0 = (w & 3) * 32;
  const int lr = lane & 15;
  const int kc = lane >> 4;

  const int4v* ap = (const int4v*)(adj + (long)(m0 + lr) * N_NODES + kc * 8);
  const bf16x8* bp0 = (const bf16x8*)(BT + (long)(n0 + lr) * N_NODES + kc * 8);
  const bf16x8* bp1 =
      (const bf16x8*)(BT + (long)(n0 + 16 + lr) * N_NODES + kc * 8);

  f32x4 acc0 = {0.f, 0.f, 0.f, 0.f};
  f32x4 acc1 = {0.f, 0.f, 0.f, 0.f};
  int degv = 0;

#pragma unroll 4
  for (int k = 0; k < N_NODES; k += 32) {
    int4v alo = ap[0];
    int4v ahi = ap[1];
    bf16x8 b0 = bp0[0];
    bf16x8 b1 = bp1[0];
    ap += 8;
    bp0 += 4;
    bp1 += 4;
    unsigned short u[8];
    u[0] = alo[0] ? 0x3F80 : 0;
    u[1] = alo[1] ? 0x3F80 : 0;
    u[2] = alo[2] ? 0x3F80 : 0;
    u[3] = alo[3] ? 0x3F80 : 0;
    u[4] = ahi[0] ? 0x3F80 : 0;
    u[5] = ahi[1] ? 0x3F80 : 0;
    u[6] = ahi[2] ? 0x3F80 : 0;
    u[7] = ahi[3] ? 0x3F80 : 0;
    degv += alo[0] + alo[1] + alo[2] + alo[3] + ahi[0] + ahi[1] + ahi[2] +
            ahi[3];
    bf16x8 a;
    memcpy(&a, u, 16);
    acc0 = __builtin_amdgcn_mfma_f32_16x16x32_bf16(a, b0, acc0, 0, 0, 0);
    acc1 = __builtin_amdgcn_mfma_f32_16x16x32_bf16(a, b1, acc1, 0, 0, 0);
  }

  degv += __shfl_xor(degv, 16);
  degv += __shfl_xor(degv, 32);
  int dgv[4];
#pragma unroll
  for (int j = 0; j < 4; ++j) dgv[j] = __shfl(degv, kc * 4 + j);

#pragma unroll
  for (int t = 0; t < 2; ++t) {
    const f32x4 acc = t ? acc1 : acc0;
    const int col = n0 + t * 16 + lr;
#pragma unroll
    for (int j = 0; j < 4; ++j) {
      const long off = (long)(m0 + kc * 4 + j) * D_FEAT + col;
      fout[off] = dgv[j] > 0 ? acc[j] * (1.0f / (float)dgv[j]) : fin[off];
    }
  }
}

// ---------------------------------------------------------------------------
extern "C" void kernel_launch(void* const* d_in, const int* in_sizes, int n_in,
                              void* d_out, int out_size, void* d_ws,
                              size_t ws_size, hipStream_t stream) {
  const float* features = (const float*)d_in[0];
  const int* adj = (const int*)d_in[1];
  float* out = (float*)d_out;
  const long NN = (long)N_NODES * N_NODES;

  const size_t PC_BYTES = 2ul * N_NODES * D_FEAT * 4;     // 8 MiB
  const size_t DEG_BYTES = 2ul * N_NODES * 2;             // 32 KiB
  const size_t BPK_BYTES = (size_t)D_FEAT * N_NODES * 2;  // 2 MiB
  const size_t NEED = PC_BYTES + DEG_BYTES + BPK_BYTES;

  if (ws_size >= NEED) {
    float* pC = (float*)d_ws;
    unsigned short* degP = (unsigned short*)((char*)d_ws + PC_BYTES);
    unsigned short* Bpk =
        (unsigned short*)((char*)d_ws + PC_BYTES + DEG_BYTES);

    // Layer 1
    bpk_build32_kernel<<<512, 256, 0, stream>>>(features, Bpk);
    fused_split2_kernel<<<512, 512, 0, stream>>>(adj, Bpk, pC, degP);
    combine2_kernel<<<1024, 256, 0, stream>>>(pC, degP, features, out);
    // Layer 2
    bpk_build32_kernel<<<512, 256, 0, stream>>>(out, Bpk);
    fused_split2_kernel<<<512, 512, 0, stream>>>(adj + NN, Bpk, pC, degP);
    combine2_kernel<<<1024, 256, 0, stream>>>(pC, degP, out, out);
  } else {
    // Fallback: round-1 verified path (needs only 2 MiB ws)
    unsigned short* BTw = (unsigned short*)d_ws;
    transpose_cast_kernel<<<N_NODES / 64, 256, 0, stream>>>(features, BTw);
    layer_kernel_direct<<<N_NODES / 32, 512, 0, stream>>>(adj, BTw, features,
                                                          out);
    transpose_cast_kernel<<<N_NODES / 64, 256, 0, stream>>>(out, BTw);
    layer_kernel_direct<<<N_NODES / 32, 512, 0, stream>>>(adj + NN, BTw, out,
                                                          out);
  }
}